// Round 1
// baseline (482.481 us; speedup 1.0000x reference)
//
#include <hip/hip_runtime.h>
#include <math.h>

typedef unsigned short u16;
typedef __attribute__((ext_vector_type(4))) float f32x4;
typedef __attribute__((ext_vector_type(8))) short bf16x8;

#define SEQ   2048
#define EMB   1024
#define NH    16
#define HD    64
#define MROWS 4096   // B*S

__device__ __forceinline__ u16 f2b(float f) {
    unsigned u = __float_as_uint(f);
    u += 0x7fff + ((u >> 16) & 1);   // RNE
    return (u16)(u >> 16);
}
__device__ __forceinline__ float b2f(u16 v) {
    return __uint_as_float(((unsigned)v) << 16);
}

// ---------------- fp32 -> bf16 convert (vectorized) ----------------
__global__ void k_f2b(const float* __restrict__ src, u16* __restrict__ dst, int n8) {
    int i = blockIdx.x * blockDim.x + threadIdx.x;
    if (i >= n8) return;
    const float4* s4 = (const float4*)src;
    float4 a = s4[i * 2], b = s4[i * 2 + 1];
    union { u16 u[8]; uint4 v; } o;
    o.u[0] = f2b(a.x); o.u[1] = f2b(a.y); o.u[2] = f2b(a.z); o.u[3] = f2b(a.w);
    o.u[4] = f2b(b.x); o.u[5] = f2b(b.y); o.u[6] = f2b(b.z); o.u[7] = f2b(b.w);
    ((uint4*)dst)[i] = o.v;
}

// ---------------- GEMM: C[M,N] = A[M,K] @ B[N,K]^T + bias ----------------
// mode 0: write bf16 to [B,H,S,D] permuted layout (QKV projections)
// mode 1: write fp32 to [M,N] row-major (final output projection)
struct GemmArgs {
    const u16* A; const u16* Bw; const float* bias; u16* Cb; float* Cf;
};

__global__ __launch_bounds__(256) void k_gemm_bt(GemmArgs g0, GemmArgs g1, GemmArgs g2,
                                                 int K, int mode) {
    GemmArgs g = (blockIdx.z == 0) ? g0 : (blockIdx.z == 1 ? g1 : g2);
    __shared__ u16 As[128 * 40];   // rows m, padded k-stride 40 (bank-conflict-safe, 16B aligned)
    __shared__ u16 Bs[128 * 40];

    int tid = threadIdx.x;
    int wave = tid >> 6, lane = tid & 63, quad = lane >> 4, l16 = lane & 15;
    int wm = wave >> 1, wn = wave & 1;
    int m0 = blockIdx.y * 128, n0 = blockIdx.x * 128;

    f32x4 acc[4][4];
#pragma unroll
    for (int i = 0; i < 4; i++)
#pragma unroll
        for (int j = 0; j < 4; j++) acc[i][j] = (f32x4){0.f, 0.f, 0.f, 0.f};

    for (int k0 = 0; k0 < K; k0 += 32) {
        // stage 128x32 bf16 tiles: 512 16B-chunks each, 2 per thread
        for (int c = tid; c < 512; c += 256) {
            int row = c >> 2, kc = (c & 3) << 3;
            *(uint4*)&As[row * 40 + kc] = *(const uint4*)&g.A[(size_t)(m0 + row) * K + k0 + kc];
            *(uint4*)&Bs[row * 40 + kc] = *(const uint4*)&g.Bw[(size_t)(n0 + row) * K + k0 + kc];
        }
        __syncthreads();
        bf16x8 af[4], bfr[4];
#pragma unroll
        for (int i = 0; i < 4; i++) af[i] = *(const bf16x8*)&As[(wm * 64 + i * 16 + l16) * 40 + quad * 8];
#pragma unroll
        for (int j = 0; j < 4; j++) bfr[j] = *(const bf16x8*)&Bs[(wn * 64 + j * 16 + l16) * 40 + quad * 8];
#pragma unroll
        for (int i = 0; i < 4; i++)
#pragma unroll
            for (int j = 0; j < 4; j++)
                acc[i][j] = __builtin_amdgcn_mfma_f32_16x16x32_bf16(af[i], bfr[j], acc[i][j], 0, 0, 0);
        __syncthreads();
    }

    if (mode == 0) {
#pragma unroll
        for (int j = 0; j < 4; j++) {
            int col = n0 + wn * 64 + j * 16 + l16;
            float bv = g.bias[col];
            int h = col >> 6, dd = col & 63;
#pragma unroll
            for (int i = 0; i < 4; i++)
#pragma unroll
                for (int r = 0; r < 4; r++) {
                    int row = m0 + wm * 64 + i * 16 + quad * 4 + r;
                    int b = row >> 11, s = row & (SEQ - 1);
                    float v = acc[i][j][r] + bv;
                    g.Cb[(((size_t)(b * NH + h) * SEQ + s) << 6) + dd] = f2b(v);
                }
        }
    } else {
#pragma unroll
        for (int i = 0; i < 4; i++)
#pragma unroll
            for (int r = 0; r < 4; r++) {
                int row = m0 + wm * 64 + i * 16 + quad * 4 + r;
#pragma unroll
                for (int j = 0; j < 4; j++) {
                    int col = n0 + wn * 64 + j * 16 + l16;
                    g.Cf[(size_t)row * EMB + col] = acc[i][j][r] + g.bias[col];
                }
            }
    }
}

// ---------------- RoPE on Q,K (bf16 [B,H,S,D] -> bf16 [B,H,S,D]) ----------------
__global__ void k_rope(const u16* __restrict__ Qp, const u16* __restrict__ Kp,
                       u16* __restrict__ Qb, u16* __restrict__ Kb) {
    int idx = blockIdx.x * 256 + threadIdx.x;   // BH*S*32 threads
    int i = idx & 31;
    int s = (idx >> 5) & (SEQ - 1);
    int bh = idx >> 16;
    size_t base = ((size_t)bh * SEQ + s) * HD;
    float inv = expf(-(float)i * 0.28782313662425575f);   // ln(10000)/32
    float ang = (float)s * inv;
    float sn, cs;
    sincosf(ang, &sn, &cs);
    float q1 = b2f(Qp[base + i]), q2 = b2f(Qp[base + i + 32]);
    Qb[base + i]      = f2b(q1 * cs - q2 * sn);
    Qb[base + i + 32] = f2b(q2 * cs + q1 * sn);
    float k1 = b2f(Kp[base + i]), k2 = b2f(Kp[base + i + 32]);
    Kb[base + i]      = f2b(k1 * cs - k2 * sn);
    Kb[base + i + 32] = f2b(k2 * cs + k1 * sn);
}

// ---------------- V transpose: [BH][S][D] -> [BH][D][S] ----------------
__global__ void k_vtrans(const u16* __restrict__ Vp, u16* __restrict__ Vt) {
    __shared__ u16 t[64 * 66];
    int bh = blockIdx.y;
    int t0 = blockIdx.x * 64;
    for (int rep = 0; rep < 16; rep++) {
        int idx = rep * 256 + threadIdx.x;
        int tt = idx >> 6, d = idx & 63;
        t[d * 66 + tt] = Vp[((size_t)bh * SEQ + t0 + tt) * HD + d];
    }
    __syncthreads();
    for (int rep = 0; rep < 16; rep++) {
        int idx = rep * 256 + threadIdx.x;
        int d = idx >> 6, tt = idx & 63;
        Vt[((size_t)bh * HD + d) * SEQ + t0 + tt] = t[d * 66 + tt];
    }
}

// ---------------- flash attention ----------------
// Q,K: bf16 [BH][S][D]; Vt: bf16 [BH][D][S]; O: bf16 [B,S,E]
// block = 4 waves; wave w handles 16 q-rows; fully wave-independent.
__global__ __launch_bounds__(256) void k_attn(const u16* __restrict__ Q,
                                              const u16* __restrict__ Kt,
                                              const u16* __restrict__ Vt,
                                              u16* __restrict__ O) {
    __shared__ u16 Pl[4][16 * 72];
    int tid = threadIdx.x;
    int w = tid >> 6, lane = tid & 63, quad = lane >> 4, l16 = lane & 15;
    int bh = blockIdx.y, qt = blockIdx.x;
    int q0 = qt * 64 + w * 16;

    size_t qbase = ((size_t)bh * SEQ + q0 + l16) * HD + quad * 8;
    bf16x8 aq0 = *(const bf16x8*)&Q[qbase];
    bf16x8 aq1 = *(const bf16x8*)&Q[qbase + 32];

    f32x4 o[4];
#pragma unroll
    for (int jd = 0; jd < 4; jd++) o[jd] = (f32x4){0.f, 0.f, 0.f, 0.f};
    float m_i[4], l_i[4];
#pragma unroll
    for (int r = 0; r < 4; r++) { m_i[r] = -INFINITY; l_i[r] = 0.f; }

    for (int t0 = 0; t0 <= q0 + 15; t0 += 64) {
        f32x4 sc[4];
#pragma unroll
        for (int j = 0; j < 4; j++) {
            sc[j] = (f32x4){0.f, 0.f, 0.f, 0.f};
            size_t kb = ((size_t)bh * SEQ + t0 + j * 16 + l16) * HD + quad * 8;
            bf16x8 b0 = *(const bf16x8*)&Kt[kb];
            bf16x8 b1 = *(const bf16x8*)&Kt[kb + 32];
            sc[j] = __builtin_amdgcn_mfma_f32_16x16x32_bf16(aq0, b0, sc[j], 0, 0, 0);
            sc[j] = __builtin_amdgcn_mfma_f32_16x16x32_bf16(aq1, b1, sc[j], 0, 0, 0);
        }
        // scale + causal mask + row max
        float rm[4];
#pragma unroll
        for (int r = 0; r < 4; r++) rm[r] = -INFINITY;
#pragma unroll
        for (int j = 0; j < 4; j++) {
            int t = t0 + j * 16 + l16;
#pragma unroll
            for (int r = 0; r < 4; r++) {
                int q = q0 + quad * 4 + r;
                float v = sc[j][r] * 0.125f;
                v = (t > q) ? -INFINITY : v;
                sc[j][r] = v;
                rm[r] = fmaxf(rm[r], v);
            }
        }
#pragma unroll
        for (int off = 1; off < 16; off <<= 1)
#pragma unroll
            for (int r = 0; r < 4; r++)
                rm[r] = fmaxf(rm[r], __shfl_xor(rm[r], off, 64));
        float alpha[4], rs[4];
#pragma unroll
        for (int r = 0; r < 4; r++) {
            float mn = fmaxf(m_i[r], rm[r]);
            alpha[r] = __expf(m_i[r] - mn);
            m_i[r] = mn;
            rs[r] = 0.f;
        }
#pragma unroll
        for (int j = 0; j < 4; j++)
#pragma unroll
            for (int r = 0; r < 4; r++) {
                float p = __expf(sc[j][r] - m_i[r]);
                sc[j][r] = p;
                rs[r] += p;
            }
#pragma unroll
        for (int off = 1; off < 16; off <<= 1)
#pragma unroll
            for (int r = 0; r < 4; r++)
                rs[r] += __shfl_xor(rs[r], off, 64);
#pragma unroll
        for (int r = 0; r < 4; r++) l_i[r] = l_i[r] * alpha[r] + rs[r];
#pragma unroll
        for (int jd = 0; jd < 4; jd++)
#pragma unroll
            for (int r = 0; r < 4; r++) o[jd][r] *= alpha[r];

        // P: C-layout -> LDS -> A-layout (wave-private region, no barrier needed)
#pragma unroll
        for (int j = 0; j < 4; j++)
#pragma unroll
            for (int r = 0; r < 4; r++)
                Pl[w][(quad * 4 + r) * 72 + j * 16 + l16] = f2b(sc[j][r]);
        bf16x8 pa0 = *(const bf16x8*)&Pl[w][l16 * 72 + quad * 8];
        bf16x8 pa1 = *(const bf16x8*)&Pl[w][l16 * 72 + 32 + quad * 8];

#pragma unroll
        for (int jd = 0; jd < 4; jd++) {
            size_t vb = ((size_t)bh * HD + jd * 16 + l16) * SEQ + t0 + quad * 8;
            bf16x8 v0 = *(const bf16x8*)&Vt[vb];
            bf16x8 v1 = *(const bf16x8*)&Vt[vb + 32];
            o[jd] = __builtin_amdgcn_mfma_f32_16x16x32_bf16(pa0, v0, o[jd], 0, 0, 0);
            o[jd] = __builtin_amdgcn_mfma_f32_16x16x32_bf16(pa1, v1, o[jd], 0, 0, 0);
        }
    }

    int b = bh >> 4, h = bh & (NH - 1);
#pragma unroll
    for (int jd = 0; jd < 4; jd++)
#pragma unroll
        for (int r = 0; r < 4; r++) {
            int q = q0 + quad * 4 + r;
            float val = o[jd][r] / l_i[r];
            O[(size_t)(b * SEQ + q) * EMB + h * HD + jd * 16 + l16] = f2b(val);
        }
}

extern "C" void kernel_launch(void* const* d_in, const int* in_sizes, int n_in,
                              void* d_out, int out_size, void* d_ws, size_t ws_size,
                              hipStream_t stream) {
    const float* query = (const float*)d_in[0];
    const float* key_  = (const float*)d_in[1];
    const float* value = (const float*)d_in[2];
    const float* Wq = (const float*)d_in[3];
    const float* bq = (const float*)d_in[4];
    const float* Wk = (const float*)d_in[5];
    const float* bk = (const float*)d_in[6];
    const float* Wv = (const float*)d_in[7];
    const float* bv = (const float*)d_in[8];
    const float* Wo = (const float*)d_in[9];
    const float* bo = (const float*)d_in[10];
    float* out = (float*)d_out;

    char* ws = (char*)d_ws;
    const size_t MB = 1u << 20;
    u16* xq  = (u16*)(ws + 0 * MB);    // later reused as Qb
    u16* xk  = (u16*)(ws + 8 * MB);    // later reused as Kb
    u16* xv  = (u16*)(ws + 16 * MB);   // later reused as Vt
    u16* wqb = (u16*)(ws + 24 * MB);
    u16* wkb = (u16*)(ws + 26 * MB);
    u16* wvb = (u16*)(ws + 28 * MB);
    u16* wob = (u16*)(ws + 30 * MB);
    u16* Qp  = (u16*)(ws + 32 * MB);   // later reused as Ab (attention out, bf16 [B,S,E])
    u16* Kp  = (u16*)(ws + 40 * MB);
    u16* Vp  = (u16*)(ws + 48 * MB);
    u16* Qb = xq; u16* Kb = xk; u16* Vt = xv; u16* Ab = Qp;

    const int NX = MROWS * EMB;   // 4,194,304
    const int NW = EMB * EMB;     // 1,048,576

    k_f2b<<<NX / (256 * 8), 256, 0, stream>>>(query, xq, NX / 8);
    k_f2b<<<NX / (256 * 8), 256, 0, stream>>>(key_,  xk, NX / 8);
    k_f2b<<<NX / (256 * 8), 256, 0, stream>>>(value, xv, NX / 8);
    k_f2b<<<NW / (256 * 8), 256, 0, stream>>>(Wq, wqb, NW / 8);
    k_f2b<<<NW / (256 * 8), 256, 0, stream>>>(Wk, wkb, NW / 8);
    k_f2b<<<NW / (256 * 8), 256, 0, stream>>>(Wv, wvb, NW / 8);
    k_f2b<<<NW / (256 * 8), 256, 0, stream>>>(Wo, wob, NW / 8);

    GemmArgs gq = { xq, wqb, bq, Qp, nullptr };
    GemmArgs gk = { xk, wkb, bk, Kp, nullptr };
    GemmArgs gv = { xv, wvb, bv, Vp, nullptr };
    k_gemm_bt<<<dim3(EMB / 128, MROWS / 128, 3), 256, 0, stream>>>(gq, gk, gv, EMB, 0);

    k_rope<<<(32 * SEQ * 32) / 256, 256, 0, stream>>>(Qp, Kp, Qb, Kb);
    k_vtrans<<<dim3(SEQ / 64, 32), 256, 0, stream>>>(Vp, Vt);
    k_attn<<<dim3(SEQ / 64, 32), 256, 0, stream>>>(Qb, Kb, Vt, Ab);

    GemmArgs go = { Ab, wob, bo, nullptr, out };
    k_gemm_bt<<<dim3(EMB / 128, MROWS / 128, 1), 256, 0, stream>>>(go, go, go, EMB, 1);
}

// Round 2
// 459.029 us; speedup vs baseline: 1.0511x; 1.0511x over previous
//
#include <hip/hip_runtime.h>
#include <math.h>

typedef unsigned short u16;
typedef __attribute__((ext_vector_type(4))) float f32x4;
typedef __attribute__((ext_vector_type(8))) short bf16x8;

#define SEQ   2048
#define EMB   1024
#define NH    16
#define HD    64
#define MROWS 4096   // B*S

__device__ __forceinline__ u16 f2b(float f) {
    unsigned u = __float_as_uint(f);
    u += 0x7fff + ((u >> 16) & 1);   // RNE
    return (u16)(u >> 16);
}
__device__ __forceinline__ unsigned pack_bf16x2(float a, float b) {
    // low16 = bf16(a), high16 = bf16(b); round-half-up (adequate for P in [0,1])
    unsigned ua = __float_as_uint(a) + 0x8000u;
    unsigned ub = __float_as_uint(b) + 0x8000u;
    return __builtin_amdgcn_perm(ub, ua, 0x07060302u);
}

// ---------------- fp32 -> bf16 converts (merged dispatches) ----------------
__global__ void k_f2b3(const float* __restrict__ s0, const float* __restrict__ s1,
                       const float* __restrict__ s2, u16* d0, u16* d1, u16* d2, int n8) {
    const float* src = (blockIdx.z == 0) ? s0 : (blockIdx.z == 1 ? s1 : s2);
    u16* dst = (blockIdx.z == 0) ? d0 : (blockIdx.z == 1 ? d1 : d2);
    int i = blockIdx.x * blockDim.x + threadIdx.x;
    if (i >= n8) return;
    const float4* s4 = (const float4*)src;
    float4 a = s4[i * 2], b = s4[i * 2 + 1];
    union { u16 u[8]; uint4 v; } o;
    o.u[0] = f2b(a.x); o.u[1] = f2b(a.y); o.u[2] = f2b(a.z); o.u[3] = f2b(a.w);
    o.u[4] = f2b(b.x); o.u[5] = f2b(b.y); o.u[6] = f2b(b.z); o.u[7] = f2b(b.w);
    ((uint4*)dst)[i] = o.v;
}
__global__ void k_f2b4(const float* __restrict__ s0, const float* __restrict__ s1,
                       const float* __restrict__ s2, const float* __restrict__ s3,
                       u16* d0, u16* d1, u16* d2, u16* d3, int n8) {
    const float* src = (blockIdx.z == 0) ? s0 : (blockIdx.z == 1 ? s1 : (blockIdx.z == 2 ? s2 : s3));
    u16* dst = (blockIdx.z == 0) ? d0 : (blockIdx.z == 1 ? d1 : (blockIdx.z == 2 ? d2 : d3));
    int i = blockIdx.x * blockDim.x + threadIdx.x;
    if (i >= n8) return;
    const float4* s4 = (const float4*)src;
    float4 a = s4[i * 2], b = s4[i * 2 + 1];
    union { u16 u[8]; uint4 v; } o;
    o.u[0] = f2b(a.x); o.u[1] = f2b(a.y); o.u[2] = f2b(a.z); o.u[3] = f2b(a.w);
    o.u[4] = f2b(b.x); o.u[5] = f2b(b.y); o.u[6] = f2b(b.z); o.u[7] = f2b(b.w);
    ((uint4*)dst)[i] = o.v;
}

// ---------------- GEMM: C[M,N] = A[M,K] @ B[N,K]^T + bias ----------------
// mode 0: QKV projections. z=0: Q (RoPE + 1/8 scale), z=1: K (RoPE), z=2: V (plain);
//         writes bf16 to [B,H,S,D].
// mode 1: output projection, fp32 to [M,N].
struct GemmArgs {
    const u16* A; const u16* Bw; const float* bias; u16* Cb; float* Cf;
};

__global__ __launch_bounds__(256) void k_gemm_bt(GemmArgs g0, GemmArgs g1, GemmArgs g2,
                                                 int K, int mode) {
    GemmArgs g = (blockIdx.z == 0) ? g0 : (blockIdx.z == 1 ? g1 : g2);
    __shared__ u16 As[128 * 40];
    __shared__ u16 Bs[128 * 40];

    int tid = threadIdx.x;
    int wave = tid >> 6, lane = tid & 63, quad = lane >> 4, l16 = lane & 15;
    int wm = wave >> 1, wn = wave & 1;
    int m0 = blockIdx.y * 128, n0 = blockIdx.x * 128;

    f32x4 acc[4][4];
#pragma unroll
    for (int i = 0; i < 4; i++)
#pragma unroll
        for (int j = 0; j < 4; j++) acc[i][j] = (f32x4){0.f, 0.f, 0.f, 0.f};

    for (int k0 = 0; k0 < K; k0 += 32) {
        for (int c = tid; c < 512; c += 256) {
            int row = c >> 2, kc = (c & 3) << 3;
            *(uint4*)&As[row * 40 + kc] = *(const uint4*)&g.A[(size_t)(m0 + row) * K + k0 + kc];
            *(uint4*)&Bs[row * 40 + kc] = *(const uint4*)&g.Bw[(size_t)(n0 + row) * K + k0 + kc];
        }
        __syncthreads();
        bf16x8 af[4], bfr[4];
#pragma unroll
        for (int i = 0; i < 4; i++) af[i] = *(const bf16x8*)&As[(wm * 64 + i * 16 + l16) * 40 + quad * 8];
#pragma unroll
        for (int j = 0; j < 4; j++) bfr[j] = *(const bf16x8*)&Bs[(wn * 64 + j * 16 + l16) * 40 + quad * 8];
#pragma unroll
        for (int i = 0; i < 4; i++)
#pragma unroll
            for (int j = 0; j < 4; j++)
                acc[i][j] = __builtin_amdgcn_mfma_f32_16x16x32_bf16(af[i], bfr[j], acc[i][j], 0, 0, 0);
        __syncthreads();
    }

    if (mode == 0) {
        float qscale = (blockIdx.z == 0) ? 0.125f : 1.0f;
        if (blockIdx.z < 2) {
            // RoPE fused: pair (dd, dd+32) = acc[i][j], acc[i][j+2], j in {0,1}
#pragma unroll
            for (int j = 0; j < 2; j++) {
                int col1 = n0 + wn * 64 + j * 16 + l16;
                int dd1 = col1 & 63;                     // in [0,32)
                int h = col1 >> 6;
                float inv = __expf(-(float)dd1 * 0.28782313662425575f);  // ln(10000)/32
                float b1 = g.bias[col1], b2 = g.bias[col1 + 32];
#pragma unroll
                for (int i = 0; i < 4; i++)
#pragma unroll
                    for (int r = 0; r < 4; r++) {
                        int row = m0 + wm * 64 + i * 16 + quad * 4 + r;
                        int b = row >> 11, s = row & (SEQ - 1);
                        float sn, cs;
                        __sincosf((float)s * inv, &sn, &cs);
                        float x1 = acc[i][j][r] + b1;
                        float x2 = acc[i][j + 2][r] + b2;
                        size_t base = ((size_t)(b * NH + h) * SEQ + s) << 6;
                        g.Cb[base + dd1]      = f2b((x1 * cs - x2 * sn) * qscale);
                        g.Cb[base + dd1 + 32] = f2b((x2 * cs + x1 * sn) * qscale);
                    }
            }
        } else {
#pragma unroll
            for (int j = 0; j < 4; j++) {
                int col = n0 + wn * 64 + j * 16 + l16;
                float bv = g.bias[col];
                int h = col >> 6, dd = col & 63;
#pragma unroll
                for (int i = 0; i < 4; i++)
#pragma unroll
                    for (int r = 0; r < 4; r++) {
                        int row = m0 + wm * 64 + i * 16 + quad * 4 + r;
                        int b = row >> 11, s = row & (SEQ - 1);
                        g.Cb[(((size_t)(b * NH + h) * SEQ + s) << 6) + dd] = f2b(acc[i][j][r] + bv);
                    }
            }
        }
    } else {
#pragma unroll
        for (int i = 0; i < 4; i++)
#pragma unroll
            for (int r = 0; r < 4; r++) {
                int row = m0 + wm * 64 + i * 16 + quad * 4 + r;
#pragma unroll
                for (int j = 0; j < 4; j++) {
                    int col = n0 + wn * 64 + j * 16 + l16;
                    g.Cf[(size_t)row * EMB + col] = acc[i][j][r] + g.bias[col];
                }
            }
    }
}

// ---------------- V transpose: [BH][S][D] -> [BH][D][S] ----------------
__global__ void k_vtrans(const u16* __restrict__ Vp, u16* __restrict__ Vt) {
    __shared__ u16 t[64 * 66];
    int bh = blockIdx.y;
    int t0 = blockIdx.x * 64;
    for (int rep = 0; rep < 16; rep++) {
        int idx = rep * 256 + threadIdx.x;
        int tt = idx >> 6, d = idx & 63;
        t[d * 66 + tt] = Vp[((size_t)bh * SEQ + t0 + tt) * HD + d];
    }
    __syncthreads();
    for (int rep = 0; rep < 16; rep++) {
        int idx = rep * 256 + threadIdx.x;
        int d = idx >> 6, tt = idx & 63;
        Vt[((size_t)bh * HD + d) * SEQ + t0 + tt] = t[d * 66 + tt];
    }
}

// ---------------- flash attention (S^T orientation) ----------------
// Q (pre-scaled 1/8), K: bf16 [BH][S][64]; Vt: bf16 [BH][64][S]; O: bf16 [B,S,E]
// Wave = 16 q-rows. Scores computed transposed (C[t][q]): q = l16 per lane, so
// softmax row-reductions are in-lane + 2 cross-quad shuffles.
__global__ __launch_bounds__(256) void k_attn(const u16* __restrict__ Q,
                                              const u16* __restrict__ K,
                                              const u16* __restrict__ Vt,
                                              u16* __restrict__ O) {
    __shared__ __align__(16) u16 Pl[4][16 * 72];
    int tid = threadIdx.x;
    int w = tid >> 6, lane = tid & 63, quad = lane >> 4, l16 = lane & 15;
    int bh = blockIdx.y;
    int q0 = (gridDim.x - 1 - blockIdx.x) * 64 + w * 16;   // long blocks first

    const u16* Qb = Q + (size_t)bh * SEQ * HD;
    const u16* Kb = K + (size_t)bh * SEQ * HD;
    const u16* Vb = Vt + (size_t)bh * HD * SEQ;
    u16* pl = Pl[w];

    // Q as B-operand fragments: n = q-local = l16, k = d
    bf16x8 bq0 = *(const bf16x8*)&Qb[(size_t)(q0 + l16) * HD + quad * 8];
    bf16x8 bq1 = *(const bf16x8*)&Qb[(size_t)(q0 + l16) * HD + quad * 8 + 32];

    f32x4 o[4];
#pragma unroll
    for (int jd = 0; jd < 4; jd++) o[jd] = (f32x4){0.f, 0.f, 0.f, 0.f};
    float m_i = -INFINITY, l_i = 0.f;

    int nmain = q0 >> 6;
    for (int it = 0; it <= nmain; ++it) {
        int t0 = it * 64;
        bool maskit = (it == nmain);

        bf16x8 ka[4][2], vb[4][2];
#pragma unroll
        for (int mt = 0; mt < 4; mt++) {
            size_t kb = (size_t)(t0 + mt * 16 + l16) * HD + quad * 8;
            ka[mt][0] = *(const bf16x8*)&Kb[kb];
            ka[mt][1] = *(const bf16x8*)&Kb[kb + 32];
        }
#pragma unroll
        for (int jd = 0; jd < 4; jd++) {
            size_t vbi = (size_t)(jd * 16 + l16) * SEQ + t0 + quad * 8;
            vb[jd][0] = *(const bf16x8*)&Vb[vbi];
            vb[jd][1] = *(const bf16x8*)&Vb[vbi + 32];
        }

        // S^T tile: C[t][q], rows t = quad*4+r (+16*mt), cols q = l16
        f32x4 sc[4];
#pragma unroll
        for (int mt = 0; mt < 4; mt++) {
            sc[mt] = (f32x4){0.f, 0.f, 0.f, 0.f};
            sc[mt] = __builtin_amdgcn_mfma_f32_16x16x32_bf16(ka[mt][0], bq0, sc[mt], 0, 0, 0);
            sc[mt] = __builtin_amdgcn_mfma_f32_16x16x32_bf16(ka[mt][1], bq1, sc[mt], 0, 0, 0);
        }

        if (maskit) {
            int q = q0 + l16;
#pragma unroll
            for (int mt = 0; mt < 4; mt++)
#pragma unroll
                for (int r = 0; r < 4; r++) {
                    int t = t0 + mt * 16 + quad * 4 + r;
                    if (t > q) sc[mt][r] = -INFINITY;
                }
        }

        // row max (per q = l16): in-lane then cross-quad
        float rm = -INFINITY;
#pragma unroll
        for (int mt = 0; mt < 4; mt++)
#pragma unroll
            for (int r = 0; r < 4; r++) rm = fmaxf(rm, sc[mt][r]);
        rm = fmaxf(rm, __shfl_xor(rm, 16, 64));
        rm = fmaxf(rm, __shfl_xor(rm, 32, 64));
        float mnew = fmaxf(m_i, rm);
        float al = __expf(m_i - mnew);
        m_i = mnew;

        float rs = 0.f;
#pragma unroll
        for (int mt = 0; mt < 4; mt++)
#pragma unroll
            for (int r = 0; r < 4; r++) {
                float p = __expf(sc[mt][r] - mnew);
                sc[mt][r] = p;
                rs += p;
            }
        rs += __shfl_xor(rs, 16, 64);
        rs += __shfl_xor(rs, 32, 64);
        l_i = l_i * al + rs;

        // stage P^T -> A-layout in LDS: row q = l16, col t
#pragma unroll
        for (int mt = 0; mt < 4; mt++) {
            uint2 pk;
            pk.x = pack_bf16x2(sc[mt][0], sc[mt][1]);
            pk.y = pack_bf16x2(sc[mt][2], sc[mt][3]);
            *(uint2*)&pl[l16 * 72 + mt * 16 + quad * 4] = pk;
        }

        // rescale O (rows q = quad*4+r): fetch alpha from lane l16 = quad*4+r
        float alr[4];
#pragma unroll
        for (int r = 0; r < 4; r++) alr[r] = __shfl(al, quad * 4 + r, 64);
#pragma unroll
        for (int jd = 0; jd < 4; jd++)
#pragma unroll
            for (int r = 0; r < 4; r++) o[jd][r] *= alr[r];

        bf16x8 pa0 = *(const bf16x8*)&pl[l16 * 72 + quad * 8];
        bf16x8 pa1 = *(const bf16x8*)&pl[l16 * 72 + 32 + quad * 8];

#pragma unroll
        for (int jd = 0; jd < 4; jd++) {
            o[jd] = __builtin_amdgcn_mfma_f32_16x16x32_bf16(pa0, vb[jd][0], o[jd], 0, 0, 0);
            o[jd] = __builtin_amdgcn_mfma_f32_16x16x32_bf16(pa1, vb[jd][1], o[jd], 0, 0, 0);
        }
    }

    float lr[4];
#pragma unroll
    for (int r = 0; r < 4; r++) lr[r] = __shfl(l_i, quad * 4 + r, 64);
    int b = bh >> 4, h = bh & (NH - 1);
#pragma unroll
    for (int jd = 0; jd < 4; jd++)
#pragma unroll
        for (int r = 0; r < 4; r++) {
            int q = q0 + quad * 4 + r;
            O[(size_t)(b * SEQ + q) * EMB + h * HD + jd * 16 + l16] = f2b(o[jd][r] / lr[r]);
        }
}

extern "C" void kernel_launch(void* const* d_in, const int* in_sizes, int n_in,
                              void* d_out, int out_size, void* d_ws, size_t ws_size,
                              hipStream_t stream) {
    const float* query = (const float*)d_in[0];
    const float* key_  = (const float*)d_in[1];
    const float* value = (const float*)d_in[2];
    const float* Wq = (const float*)d_in[3];
    const float* bq = (const float*)d_in[4];
    const float* Wk = (const float*)d_in[5];
    const float* bk = (const float*)d_in[6];
    const float* Wv = (const float*)d_in[7];
    const float* bv = (const float*)d_in[8];
    const float* Wo = (const float*)d_in[9];
    const float* bo = (const float*)d_in[10];
    float* out = (float*)d_out;

    char* ws = (char*)d_ws;
    const size_t MB = 1u << 20;
    u16* xq  = (u16*)(ws + 0 * MB);    // reused as Vt after QKV GEMM
    u16* xk  = (u16*)(ws + 8 * MB);    // reused as Ab (attn out)
    u16* xv  = (u16*)(ws + 16 * MB);
    u16* wqb = (u16*)(ws + 24 * MB);
    u16* wkb = (u16*)(ws + 26 * MB);
    u16* wvb = (u16*)(ws + 28 * MB);
    u16* wob = (u16*)(ws + 30 * MB);
    u16* Qp  = (u16*)(ws + 32 * MB);   // Q with RoPE+scale, [B,H,S,D]
    u16* Kp  = (u16*)(ws + 40 * MB);   // K with RoPE
    u16* Vp  = (u16*)(ws + 48 * MB);   // V plain
    u16* Vt = xq;
    u16* Ab = xk;

    const int NX = MROWS * EMB;
    const int NW = EMB * EMB;

    k_f2b3<<<dim3(NX / (256 * 8), 1, 3), 256, 0, stream>>>(query, key_, value, xq, xk, xv, NX / 8);
    k_f2b4<<<dim3(NW / (256 * 8), 1, 4), 256, 0, stream>>>(Wq, Wk, Wv, Wo, wqb, wkb, wvb, wob, NW / 8);

    GemmArgs gq = { xq, wqb, bq, Qp, nullptr };
    GemmArgs gk = { xk, wkb, bk, Kp, nullptr };
    GemmArgs gv = { xv, wvb, bv, Vp, nullptr };
    k_gemm_bt<<<dim3(EMB / 128, MROWS / 128, 3), 256, 0, stream>>>(gq, gk, gv, EMB, 0);

    k_vtrans<<<dim3(SEQ / 64, 32), 256, 0, stream>>>(Vp, Vt);
    k_attn<<<dim3(SEQ / 64, 32), 256, 0, stream>>>(Qp, Kp, Vt, Ab);

    GemmArgs go = { Ab, wob, bo, nullptr, out };
    k_gemm_bt<<<dim3(EMB / 128, MROWS / 128, 1), 256, 0, stream>>>(go, go, go, EMB, 1);
}

// Round 3
// 259.693 us; speedup vs baseline: 1.8579x; 1.7676x over previous
//
#include <hip/hip_runtime.h>
#include <math.h>

typedef unsigned short u16;
typedef __attribute__((ext_vector_type(4))) float f32x4;
typedef __attribute__((ext_vector_type(8))) short bf16x8;

#define SEQ   2048
#define EMB   1024
#define NH    16
#define HD    64
#define MROWS 4096   // B*S

__device__ __forceinline__ u16 f2b(float f) {
    unsigned u = __float_as_uint(f);
    u += 0x7fff + ((u >> 16) & 1);   // RNE
    return (u16)(u >> 16);
}
__device__ __forceinline__ unsigned pack_bf16x2(float a, float b) {
    unsigned ua = __float_as_uint(a) + 0x8000u;
    unsigned ub = __float_as_uint(b) + 0x8000u;
    return __builtin_amdgcn_perm(ub, ua, 0x07060302u);
}
__device__ __forceinline__ void gld16(const u16* g, const u16* l) {
    __builtin_amdgcn_global_load_lds((const __attribute__((address_space(1))) void*)g,
                                     (__attribute__((address_space(3))) void*)l, 16, 0, 0);
}

// ---------------- fp32 -> bf16 converts ----------------
__global__ void k_f2b3(const float* __restrict__ s0, const float* __restrict__ s1,
                       const float* __restrict__ s2, u16* d0, u16* d1, u16* d2, int n8) {
    const float* src = (blockIdx.z == 0) ? s0 : (blockIdx.z == 1 ? s1 : s2);
    u16* dst = (blockIdx.z == 0) ? d0 : (blockIdx.z == 1 ? d1 : d2);
    int i = blockIdx.x * blockDim.x + threadIdx.x;
    if (i >= n8) return;
    const float4* s4 = (const float4*)src;
    float4 a = s4[i * 2], b = s4[i * 2 + 1];
    union { u16 u[8]; uint4 v; } o;
    o.u[0] = f2b(a.x); o.u[1] = f2b(a.y); o.u[2] = f2b(a.z); o.u[3] = f2b(a.w);
    o.u[4] = f2b(b.x); o.u[5] = f2b(b.y); o.u[6] = f2b(b.z); o.u[7] = f2b(b.w);
    ((uint4*)dst)[i] = o.v;
}
__global__ void k_f2b4(const float* __restrict__ s0, const float* __restrict__ s1,
                       const float* __restrict__ s2, const float* __restrict__ s3,
                       u16* d0, u16* d1, u16* d2, u16* d3, int n8) {
    const float* src = (blockIdx.z == 0) ? s0 : (blockIdx.z == 1 ? s1 : (blockIdx.z == 2 ? s2 : s3));
    u16* dst = (blockIdx.z == 0) ? d0 : (blockIdx.z == 1 ? d1 : (blockIdx.z == 2 ? d2 : d3));
    int i = blockIdx.x * blockDim.x + threadIdx.x;
    if (i >= n8) return;
    const float4* s4 = (const float4*)src;
    float4 a = s4[i * 2], b = s4[i * 2 + 1];
    union { u16 u[8]; uint4 v; } o;
    o.u[0] = f2b(a.x); o.u[1] = f2b(a.y); o.u[2] = f2b(a.z); o.u[3] = f2b(a.w);
    o.u[4] = f2b(b.x); o.u[5] = f2b(b.y); o.u[6] = f2b(b.z); o.u[7] = f2b(b.w);
    ((uint4*)dst)[i] = o.v;
}

// ---------------- GEMM: C[M,N] = A[M,K] @ B[N,K]^T + bias ----------------
// mode 0: QKV projections. z=0: Q (RoPE + scale incl log2e), z=1: K (RoPE),
//         z=2: V -> transposed [BH][D][S]. All bf16.
// mode 1: output projection, fp32 row-major.
struct GemmArgs {
    const u16* A; const u16* Bw; const float* bias; u16* Cb; float* Cf;
};

__global__ __launch_bounds__(256) void k_gemm_bt(GemmArgs g0, GemmArgs g1, GemmArgs g2,
                                                 int K, int mode) {
    GemmArgs g = (blockIdx.z == 0) ? g0 : (blockIdx.z == 1 ? g1 : g2);
    // double-buffered: per buffer A tile 128x32 (4096 u16), B tile 128x32 (4096 u16)
    __shared__ u16 sbuf[2][8192];

    int tid = threadIdx.x;
    int wave = tid >> 6, lane = tid & 63, quad = lane >> 4, l16 = lane & 15;
    int wm = wave >> 1, wn = wave & 1;
    int m0 = blockIdx.y * 128, n0 = blockIdx.x * 128;

    auto stage = [&](int k0, u16* buf) {
#pragma unroll
        for (int pp = 0; pp < 4; pp++) {
            int slot = pp * 256 + tid;          // 0..1023
            int p = slot & 3;
            const u16* gsrc;
            if (pp < 2) {
                int row = slot >> 2;            // 0..127
                int c = p ^ (row & 3);
                gsrc = g.A + (size_t)(m0 + row) * K + k0 + c * 8;
            } else {
                int row = (slot >> 2) - 128;
                int c = p ^ (row & 3);
                gsrc = g.Bw + (size_t)(n0 + row) * K + k0 + c * 8;
            }
            gld16(gsrc, buf + slot * 8);
        }
    };

    f32x4 acc[4][4];
#pragma unroll
    for (int i = 0; i < 4; i++)
#pragma unroll
        for (int j = 0; j < 4; j++) acc[i][j] = (f32x4){0.f, 0.f, 0.f, 0.f};

    int nk = K >> 5;
    stage(0, sbuf[0]);
    for (int ks = 0; ks < nk; ks++) {
        __syncthreads();                         // drains DMA for sbuf[ks&1]
        if (ks + 1 < nk) stage((ks + 1) << 5, sbuf[(ks + 1) & 1]);
        const u16* Ab = sbuf[ks & 1];
        const u16* Bb = Ab + 4096;
        bf16x8 af[4], bfr[4];
#pragma unroll
        for (int i = 0; i < 4; i++) {
            int row = wm * 64 + i * 16 + l16;
            af[i] = *(const bf16x8*)&Ab[row * 32 + (quad ^ (row & 3)) * 8];
        }
#pragma unroll
        for (int j = 0; j < 4; j++) {
            int row = wn * 64 + j * 16 + l16;
            bfr[j] = *(const bf16x8*)&Bb[row * 32 + (quad ^ (row & 3)) * 8];
        }
#pragma unroll
        for (int i = 0; i < 4; i++)
#pragma unroll
            for (int j = 0; j < 4; j++)
                acc[i][j] = __builtin_amdgcn_mfma_f32_16x16x32_bf16(af[i], bfr[j], acc[i][j], 0, 0, 0);
    }

    if (mode == 0) {
        if (blockIdx.z < 2) {
            float qscale = (blockIdx.z == 0) ? 0.18033688011112042f : 1.0f;  // (1/8)*log2(e) for Q
#pragma unroll
            for (int j = 0; j < 2; j++) {
                int col1 = n0 + wn * 64 + j * 16 + l16;
                int dd1 = col1 & 63;                     // in [0,32)
                int h = col1 >> 6;
                float inv = __expf(-(float)dd1 * 0.28782313662425575f);  // ln(10000)/32
                float b1 = g.bias[col1], b2 = g.bias[col1 + 32];
#pragma unroll
                for (int i = 0; i < 4; i++)
#pragma unroll
                    for (int r = 0; r < 4; r++) {
                        int row = m0 + wm * 64 + i * 16 + quad * 4 + r;
                        int b = row >> 11, s = row & (SEQ - 1);
                        float sn, cs;
                        __sincosf((float)s * inv, &sn, &cs);
                        float x1 = acc[i][j][r] + b1;
                        float x2 = acc[i][j + 2][r] + b2;
                        size_t base = ((size_t)(b * NH + h) * SEQ + s) << 6;
                        g.Cb[base + dd1]      = f2b((x1 * cs - x2 * sn) * qscale);
                        g.Cb[base + dd1 + 32] = f2b((x2 * cs + x1 * sn) * qscale);
                    }
            }
        } else {
            // V: write transposed [BH][D][S]
#pragma unroll
            for (int j = 0; j < 4; j++) {
                int col = n0 + wn * 64 + j * 16 + l16;
                float bv = g.bias[col];
                int h = col >> 6, dd = col & 63;
#pragma unroll
                for (int i = 0; i < 4; i++)
#pragma unroll
                    for (int r = 0; r < 4; r++) {
                        int row = m0 + wm * 64 + i * 16 + quad * 4 + r;
                        int b = row >> 11, s = row & (SEQ - 1);
                        g.Cb[((size_t)((b * NH + h) * HD) + dd) * SEQ + s] = f2b(acc[i][j][r] + bv);
                    }
            }
        }
    } else {
#pragma unroll
        for (int i = 0; i < 4; i++)
#pragma unroll
            for (int r = 0; r < 4; r++) {
                int row = m0 + wm * 64 + i * 16 + quad * 4 + r;
#pragma unroll
                for (int j = 0; j < 4; j++) {
                    int col = n0 + wn * 64 + j * 16 + l16;
                    g.Cf[(size_t)row * EMB + col] = acc[i][j][r] + g.bias[col];
                }
            }
    }
}

// ---------------- flash attention (S^T orientation, LDS-staged K/V) ----------------
// Q (pre-scaled by 0.125*log2e), K: bf16 [BH][S][64]; Vt: bf16 [BH][64][S]; O: bf16 [B,S,E]
__global__ __launch_bounds__(256) void k_attn(const u16* __restrict__ Q,
                                              const u16* __restrict__ K,
                                              const u16* __restrict__ Vt,
                                              u16* __restrict__ O) {
    // per buffer: K tile 64x64 (4096 u16) + V tile 64x64 (4096 u16); XOR-swizzled rows of 8 chunks
    __shared__ u16 sbuf[2][8192];
    __shared__ u16 Pl[4][1024];                  // per-wave P^T, 16 rows x 64, swizzled
    int tid = threadIdx.x;
    int w = tid >> 6, lane = tid & 63, quad = lane >> 4, l16 = lane & 15;
    int bh = blockIdx.y;
    int qt = gridDim.x - 1 - blockIdx.x;         // long blocks first
    int q0 = qt * 64 + w * 16;

    const u16* Qb = Q + (size_t)bh * SEQ * HD;
    const u16* Kb = K + (size_t)bh * SEQ * HD;
    const u16* Vb = Vt + (size_t)bh * HD * SEQ;
    u16* pl = Pl[w];

    auto stage = [&](int t0, u16* buf) {
#pragma unroll
        for (int pp = 0; pp < 4; pp++) {
            int slot = pp * 256 + tid;           // 0..1023
            int r = (slot >> 3) & 63;
            int p = slot & 7;
            int c = p ^ (r & 7);
            const u16* gsrc = (pp < 2) ? Kb + (size_t)(t0 + r) * HD + c * 8
                                       : Vb + (size_t)r * SEQ + t0 + c * 8;
            gld16(gsrc, buf + slot * 8);
        }
    };

    // Q as B-operand fragments: n = q-local = l16, k = d
    bf16x8 bq0 = *(const bf16x8*)&Qb[(size_t)(q0 + l16) * HD + quad * 8];
    bf16x8 bq1 = *(const bf16x8*)&Qb[(size_t)(q0 + l16) * HD + quad * 8 + 32];

    f32x4 o[4];
#pragma unroll
    for (int jd = 0; jd < 4; jd++) o[jd] = (f32x4){0.f, 0.f, 0.f, 0.f};
    float m_i = -INFINITY, l_i = 0.f;

    int nmain = qt;                              // same for all 4 waves
    stage(0, sbuf[0]);
    for (int it = 0; it <= nmain; ++it) {
        __syncthreads();                         // drains DMA for sbuf[it&1]
        if (it < nmain) stage((it + 1) * 64, sbuf[(it + 1) & 1]);
        const u16* Kl = sbuf[it & 1];
        const u16* Vl = Kl + 4096;
        int t0 = it * 64;

        // S^T tile: C[t][q], rows t = quad*4+r (+16*mt), cols q = l16
        f32x4 sc[4];
#pragma unroll
        for (int mt = 0; mt < 4; mt++) {
            int row = mt * 16 + l16;
            bf16x8 k0 = *(const bf16x8*)&Kl[row * 64 + (quad ^ (row & 7)) * 8];
            bf16x8 k1 = *(const bf16x8*)&Kl[row * 64 + ((quad + 4) ^ (row & 7)) * 8];
            sc[mt] = (f32x4){0.f, 0.f, 0.f, 0.f};
            sc[mt] = __builtin_amdgcn_mfma_f32_16x16x32_bf16(k0, bq0, sc[mt], 0, 0, 0);
            sc[mt] = __builtin_amdgcn_mfma_f32_16x16x32_bf16(k1, bq1, sc[mt], 0, 0, 0);
        }

        if (it == nmain) {
            int q = q0 + l16;
#pragma unroll
            for (int mt = 0; mt < 4; mt++)
#pragma unroll
                for (int r = 0; r < 4; r++) {
                    int t = t0 + mt * 16 + quad * 4 + r;
                    if (t > q) sc[mt][r] = -INFINITY;
                }
        }

        float rm = -INFINITY;
#pragma unroll
        for (int mt = 0; mt < 4; mt++)
#pragma unroll
            for (int r = 0; r < 4; r++) rm = fmaxf(rm, sc[mt][r]);
        rm = fmaxf(rm, __shfl_xor(rm, 16, 64));
        rm = fmaxf(rm, __shfl_xor(rm, 32, 64));
        float mnew = fmaxf(m_i, rm);
        float al = __builtin_amdgcn_exp2f(m_i - mnew);
        m_i = mnew;

        float rs = 0.f;
#pragma unroll
        for (int mt = 0; mt < 4; mt++)
#pragma unroll
            for (int r = 0; r < 4; r++) {
                float p = __builtin_amdgcn_exp2f(sc[mt][r] - mnew);
                sc[mt][r] = p;
                rs += p;
            }
        rs += __shfl_xor(rs, 16, 64);
        rs += __shfl_xor(rs, 32, 64);
        l_i = l_i * al + rs;

        // stage P^T (row q = l16, cols t), XOR-swizzled 16B chunks
#pragma unroll
        for (int mt = 0; mt < 4; mt++) {
            uint2 pk;
            pk.x = pack_bf16x2(sc[mt][0], sc[mt][1]);
            pk.y = pack_bf16x2(sc[mt][2], sc[mt][3]);
            int chunk = 2 * mt + (quad >> 1);
            *(uint2*)&pl[l16 * 64 + (chunk ^ (l16 & 7)) * 8 + (quad & 1) * 4] = pk;
        }

        float alr[4];
#pragma unroll
        for (int r = 0; r < 4; r++) alr[r] = __shfl(al, quad * 4 + r, 64);
#pragma unroll
        for (int jd = 0; jd < 4; jd++)
#pragma unroll
            for (int r = 0; r < 4; r++) o[jd][r] *= alr[r];

        bf16x8 pa0 = *(const bf16x8*)&pl[l16 * 64 + (quad ^ (l16 & 7)) * 8];
        bf16x8 pa1 = *(const bf16x8*)&pl[l16 * 64 + ((quad + 4) ^ (l16 & 7)) * 8];

#pragma unroll
        for (int jd = 0; jd < 4; jd++) {
            int drow = jd * 16 + l16;
            bf16x8 v0 = *(const bf16x8*)&Vl[drow * 64 + (quad ^ (drow & 7)) * 8];
            bf16x8 v1 = *(const bf16x8*)&Vl[drow * 64 + ((quad + 4) ^ (drow & 7)) * 8];
            o[jd] = __builtin_amdgcn_mfma_f32_16x16x32_bf16(pa0, v0, o[jd], 0, 0, 0);
            o[jd] = __builtin_amdgcn_mfma_f32_16x16x32_bf16(pa1, v1, o[jd], 0, 0, 0);
        }
    }

    float lr[4];
#pragma unroll
    for (int r = 0; r < 4; r++) lr[r] = __shfl(l_i, quad * 4 + r, 64);
    int b = bh >> 4, h = bh & (NH - 1);
#pragma unroll
    for (int jd = 0; jd < 4; jd++)
#pragma unroll
        for (int r = 0; r < 4; r++) {
            int q = q0 + quad * 4 + r;
            O[(size_t)(b * SEQ + q) * EMB + h * HD + jd * 16 + l16] = f2b(o[jd][r] / lr[r]);
        }
}

extern "C" void kernel_launch(void* const* d_in, const int* in_sizes, int n_in,
                              void* d_out, int out_size, void* d_ws, size_t ws_size,
                              hipStream_t stream) {
    const float* query = (const float*)d_in[0];
    const float* key_  = (const float*)d_in[1];
    const float* value = (const float*)d_in[2];
    const float* Wq = (const float*)d_in[3];
    const float* bq = (const float*)d_in[4];
    const float* Wk = (const float*)d_in[5];
    const float* bk = (const float*)d_in[6];
    const float* Wv = (const float*)d_in[7];
    const float* bv = (const float*)d_in[8];
    const float* Wo = (const float*)d_in[9];
    const float* bo = (const float*)d_in[10];
    float* out = (float*)d_out;

    char* ws = (char*)d_ws;
    const size_t MB = 1u << 20;
    u16* xq  = (u16*)(ws + 0 * MB);
    u16* xk  = (u16*)(ws + 8 * MB);    // reused as Ab (attn out) after K-proj GEMM
    u16* xv  = (u16*)(ws + 16 * MB);
    u16* wqb = (u16*)(ws + 24 * MB);
    u16* wkb = (u16*)(ws + 26 * MB);
    u16* wvb = (u16*)(ws + 28 * MB);
    u16* wob = (u16*)(ws + 30 * MB);
    u16* Qp  = (u16*)(ws + 32 * MB);   // Q with RoPE+scale, [B,H,S,D]
    u16* Kp  = (u16*)(ws + 40 * MB);   // K with RoPE, [B,H,S,D]
    u16* Vt  = (u16*)(ws + 48 * MB);   // V transposed, [B,H,D,S]
    u16* Ab  = xk;

    const int NX = MROWS * EMB;
    const int NW = EMB * EMB;

    k_f2b3<<<dim3(NX / (256 * 8), 1, 3), 256, 0, stream>>>(query, key_, value, xq, xk, xv, NX / 8);
    k_f2b4<<<dim3(NW / (256 * 8), 1, 4), 256, 0, stream>>>(Wq, Wk, Wv, Wo, wqb, wkb, wvb, wob, NW / 8);

    GemmArgs gq = { xq, wqb, bq, Qp, nullptr };
    GemmArgs gk = { xk, wkb, bk, Kp, nullptr };
    GemmArgs gv = { xv, wvb, bv, Vt, nullptr };
    k_gemm_bt<<<dim3(EMB / 128, MROWS / 128, 3), 256, 0, stream>>>(gq, gk, gv, EMB, 0);

    k_attn<<<dim3(SEQ / 64, 32), 256, 0, stream>>>(Qp, Kp, Vt, Ab);

    GemmArgs go = { Ab, wob, bo, nullptr, out };
    k_gemm_bt<<<dim3(EMB / 128, MROWS / 128, 1), 256, 0, stream>>>(go, go, go, EMB, 1);
}

// Round 4
// 242.540 us; speedup vs baseline: 1.9893x; 1.0707x over previous
//
#include <hip/hip_runtime.h>
#include <math.h>

typedef unsigned short u16;
typedef __attribute__((ext_vector_type(4))) float f32x4;
typedef __attribute__((ext_vector_type(8))) short bf16x8;

#define SEQ   2048
#define EMB   1024
#define NH    16
#define HD    64
#define MROWS 4096   // B*S

__device__ __forceinline__ u16 f2b(float f) {
    unsigned u = __float_as_uint(f);
    u += 0x7fff + ((u >> 16) & 1);   // RNE
    return (u16)(u >> 16);
}
__device__ __forceinline__ unsigned pack_bf16x2(float a, float b) {
    unsigned ua = __float_as_uint(a) + 0x8000u;
    unsigned ub = __float_as_uint(b) + 0x8000u;
    return __builtin_amdgcn_perm(ub, ua, 0x07060302u);
}
__device__ __forceinline__ void gld16(const u16* g, const u16* l) {
    __builtin_amdgcn_global_load_lds((const __attribute__((address_space(1))) void*)g,
                                     (__attribute__((address_space(3))) void*)l, 16, 0, 0);
}

// ---------------- fp32 -> bf16 converts ----------------
__global__ void k_f2b3(const float* __restrict__ s0, const float* __restrict__ s1,
                       const float* __restrict__ s2, u16* d0, u16* d1, u16* d2, int n8) {
    const float* src = (blockIdx.z == 0) ? s0 : (blockIdx.z == 1 ? s1 : s2);
    u16* dst = (blockIdx.z == 0) ? d0 : (blockIdx.z == 1 ? d1 : d2);
    int i = blockIdx.x * blockDim.x + threadIdx.x;
    if (i >= n8) return;
    const float4* s4 = (const float4*)src;
    float4 a = s4[i * 2], b = s4[i * 2 + 1];
    union { u16 u[8]; uint4 v; } o;
    o.u[0] = f2b(a.x); o.u[1] = f2b(a.y); o.u[2] = f2b(a.z); o.u[3] = f2b(a.w);
    o.u[4] = f2b(b.x); o.u[5] = f2b(b.y); o.u[6] = f2b(b.z); o.u[7] = f2b(b.w);
    ((uint4*)dst)[i] = o.v;
}
__global__ void k_f2b4(const float* __restrict__ s0, const float* __restrict__ s1,
                       const float* __restrict__ s2, const float* __restrict__ s3,
                       u16* d0, u16* d1, u16* d2, u16* d3, int n8) {
    const float* src = (blockIdx.z == 0) ? s0 : (blockIdx.z == 1 ? s1 : (blockIdx.z == 2 ? s2 : s3));
    u16* dst = (blockIdx.z == 0) ? d0 : (blockIdx.z == 1 ? d1 : (blockIdx.z == 2 ? d2 : d3));
    int i = blockIdx.x * blockDim.x + threadIdx.x;
    if (i >= n8) return;
    const float4* s4 = (const float4*)src;
    float4 a = s4[i * 2], b = s4[i * 2 + 1];
    union { u16 u[8]; uint4 v; } o;
    o.u[0] = f2b(a.x); o.u[1] = f2b(a.y); o.u[2] = f2b(a.z); o.u[3] = f2b(a.w);
    o.u[4] = f2b(b.x); o.u[5] = f2b(b.y); o.u[6] = f2b(b.z); o.u[7] = f2b(b.w);
    ((uint4*)dst)[i] = o.v;
}

// ---------------- GEMM: C[M,N] = A[M,K] @ B[N,K]^T + bias ----------------
struct GemmArgs {
    const u16* A; const u16* Bw; const float* bias; u16* Cb; float* Cf;
};

__global__ __launch_bounds__(256) void k_gemm_bt(GemmArgs g0, GemmArgs g1, GemmArgs g2,
                                                 int K, int mode) {
    GemmArgs g = (blockIdx.z == 0) ? g0 : (blockIdx.z == 1 ? g1 : g2);
    __shared__ u16 sbuf[2][8192];

    int tid = threadIdx.x;
    int wave = tid >> 6, lane = tid & 63, quad = lane >> 4, l16 = lane & 15;
    int wm = wave >> 1, wn = wave & 1;
    int m0 = blockIdx.y * 128, n0 = blockIdx.x * 128;

    auto stage = [&](int k0, u16* buf) {
#pragma unroll
        for (int pp = 0; pp < 4; pp++) {
            int slot = pp * 256 + tid;
            int p = slot & 3;
            const u16* gsrc;
            if (pp < 2) {
                int row = slot >> 2;
                int c = p ^ (row & 3);
                gsrc = g.A + (size_t)(m0 + row) * K + k0 + c * 8;
            } else {
                int row = (slot >> 2) - 128;
                int c = p ^ (row & 3);
                gsrc = g.Bw + (size_t)(n0 + row) * K + k0 + c * 8;
            }
            gld16(gsrc, buf + slot * 8);
        }
    };

    f32x4 acc[4][4];
#pragma unroll
    for (int i = 0; i < 4; i++)
#pragma unroll
        for (int j = 0; j < 4; j++) acc[i][j] = (f32x4){0.f, 0.f, 0.f, 0.f};

    int nk = K >> 5;
    stage(0, sbuf[0]);
    for (int ks = 0; ks < nk; ks++) {
        __syncthreads();
        if (ks + 1 < nk) stage((ks + 1) << 5, sbuf[(ks + 1) & 1]);
        const u16* Ab = sbuf[ks & 1];
        const u16* Bb = Ab + 4096;
        bf16x8 af[4], bfr[4];
#pragma unroll
        for (int i = 0; i < 4; i++) {
            int row = wm * 64 + i * 16 + l16;
            af[i] = *(const bf16x8*)&Ab[row * 32 + (quad ^ (row & 3)) * 8];
        }
#pragma unroll
        for (int j = 0; j < 4; j++) {
            int row = wn * 64 + j * 16 + l16;
            bfr[j] = *(const bf16x8*)&Bb[row * 32 + (quad ^ (row & 3)) * 8];
        }
#pragma unroll
        for (int i = 0; i < 4; i++)
#pragma unroll
            for (int j = 0; j < 4; j++)
                acc[i][j] = __builtin_amdgcn_mfma_f32_16x16x32_bf16(af[i], bfr[j], acc[i][j], 0, 0, 0);
    }

    if (mode == 0) {
        if (blockIdx.z < 2) {
            float qscale = (blockIdx.z == 0) ? 0.18033688011112042f : 1.0f;  // (1/8)*log2(e) for Q
#pragma unroll
            for (int j = 0; j < 2; j++) {
                int col1 = n0 + wn * 64 + j * 16 + l16;
                int dd1 = col1 & 63;
                int h = col1 >> 6;
                float inv = __expf(-(float)dd1 * 0.28782313662425575f);  // ln(10000)/32
                float b1 = g.bias[col1], b2 = g.bias[col1 + 32];
#pragma unroll
                for (int i = 0; i < 4; i++)
#pragma unroll
                    for (int r = 0; r < 4; r++) {
                        int row = m0 + wm * 64 + i * 16 + quad * 4 + r;
                        int b = row >> 11, s = row & (SEQ - 1);
                        float sn, cs;
                        __sincosf((float)s * inv, &sn, &cs);
                        float x1 = acc[i][j][r] + b1;
                        float x2 = acc[i][j + 2][r] + b2;
                        size_t base = ((size_t)(b * NH + h) * SEQ + s) << 6;
                        g.Cb[base + dd1]      = f2b((x1 * cs - x2 * sn) * qscale);
                        g.Cb[base + dd1 + 32] = f2b((x2 * cs + x1 * sn) * qscale);
                    }
            }
        } else {
            // V: write transposed [BH][D][S]
#pragma unroll
            for (int j = 0; j < 4; j++) {
                int col = n0 + wn * 64 + j * 16 + l16;
                float bv = g.bias[col];
                int h = col >> 6, dd = col & 63;
#pragma unroll
                for (int i = 0; i < 4; i++)
#pragma unroll
                    for (int r = 0; r < 4; r++) {
                        int row = m0 + wm * 64 + i * 16 + quad * 4 + r;
                        int b = row >> 11, s = row & (SEQ - 1);
                        g.Cb[((size_t)((b * NH + h) * HD) + dd) * SEQ + s] = f2b(acc[i][j][r] + bv);
                    }
            }
        }
    } else {
#pragma unroll
        for (int i = 0; i < 4; i++)
#pragma unroll
            for (int r = 0; r < 4; r++) {
                int row = m0 + wm * 64 + i * 16 + quad * 4 + r;
#pragma unroll
                for (int j = 0; j < 4; j++) {
                    int col = n0 + wn * 64 + j * 16 + l16;
                    g.Cf[(size_t)row * EMB + col] = acc[i][j][r] + g.bias[col];
                }
            }
    }
}

// ---------------- flash attention ----------------
// q-tile 128/block: 4 waves x 32 rows (2 groups of 16). O accumulated transposed
// (C[d][q], q = l16) so alpha/l are per-lane. K/V LDS-staged via DMA, double-buffered.
__global__ __launch_bounds__(256, 2) void k_attn(const u16* __restrict__ Q,
                                                 const u16* __restrict__ K,
                                                 const u16* __restrict__ Vt,
                                                 u16* __restrict__ O) {
    __shared__ u16 sbuf[2][8192];                // K tile 64x64 + V tile 64x64 per buffer
    __shared__ u16 Pl[4][3072];                  // per-wave: P staging (2x1024) / epilogue; pads LDS to 56KB -> 2 blocks/CU
    int tid = threadIdx.x;
    int w = tid >> 6, lane = tid & 63, quad = lane >> 4, l16 = lane & 15;
    int bh = blockIdx.y;
    // complementary pairing: blocks b and b+256 land on ~same CU with qt and 15-qt
    int qt = (blockIdx.y & 16) ? blockIdx.x : (15 - blockIdx.x);
    int q0w = qt * 128 + w * 32;

    const u16* Qb = Q + (size_t)bh * SEQ * HD;
    const u16* Kb = K + (size_t)bh * SEQ * HD;
    const u16* Vb = Vt + (size_t)bh * HD * SEQ;
    u16* pl = Pl[w];

    auto stage = [&](int t0, u16* buf) {
#pragma unroll
        for (int pp = 0; pp < 4; pp++) {
            int slot = pp * 256 + tid;
            int r = (slot >> 3) & 63;
            int p = slot & 7;
            int c = p ^ (r & 7);
            const u16* gsrc = (pp < 2) ? Kb + (size_t)(t0 + r) * HD + c * 8
                                       : Vb + (size_t)r * SEQ + t0 + c * 8;
            gld16(gsrc, buf + slot * 8);
        }
    };

    // Q B-operand fragments for both groups: n = q-local = l16, k = d
    bf16x8 bq[2][2];
#pragma unroll
    for (int g = 0; g < 2; g++) {
        size_t base = (size_t)(q0w + g * 16 + l16) * HD + quad * 8;
        bq[g][0] = *(const bf16x8*)&Qb[base];
        bq[g][1] = *(const bf16x8*)&Qb[base + 32];
    }

    f32x4 o2[2][4];
#pragma unroll
    for (int g = 0; g < 2; g++)
#pragma unroll
        for (int jd = 0; jd < 4; jd++) o2[g][jd] = (f32x4){0.f, 0.f, 0.f, 0.f};
    float m_i[2] = {-INFINITY, -INFINITY};
    float l_p[2] = {0.f, 0.f};

    int niter = 2 * qt + 2;
    stage(0, sbuf[0]);
    for (int it = 0; it < niter; ++it) {
        __syncthreads();
        if (it + 1 < niter) stage((it + 1) * 64, sbuf[(it + 1) & 1]);
        const u16* Kl = sbuf[it & 1];
        const u16* Vl = Kl + 4096;
        int t0 = it * 64;

        // shared K (A-op) and V (A-op) fragments for both groups
        bf16x8 kf[4][2], vf[4][2];
#pragma unroll
        for (int mt = 0; mt < 4; mt++) {
            int row = mt * 16 + l16;
            kf[mt][0] = *(const bf16x8*)&Kl[row * 64 + (quad ^ (row & 7)) * 8];
            kf[mt][1] = *(const bf16x8*)&Kl[row * 64 + ((quad + 4) ^ (row & 7)) * 8];
            vf[mt][0] = *(const bf16x8*)&Vl[row * 64 + (quad ^ (row & 7)) * 8];
            vf[mt][1] = *(const bf16x8*)&Vl[row * 64 + ((quad + 4) ^ (row & 7)) * 8];
        }

#pragma unroll
        for (int g = 0; g < 2; g++) {
            int qmin = q0w + g * 16;
            if (t0 > qmin + 15) continue;        // tile fully masked for this group (wave-uniform)

            // S^T tile: C[t][q], rows t = 16mt+quad*4+r, cols q = l16
            f32x4 sc[4];
#pragma unroll
            for (int mt = 0; mt < 4; mt++) {
                sc[mt] = (f32x4){0.f, 0.f, 0.f, 0.f};
                sc[mt] = __builtin_amdgcn_mfma_f32_16x16x32_bf16(kf[mt][0], bq[g][0], sc[mt], 0, 0, 0);
                sc[mt] = __builtin_amdgcn_mfma_f32_16x16x32_bf16(kf[mt][1], bq[g][1], sc[mt], 0, 0, 0);
            }

            if (t0 + 63 > qmin) {
                int q = qmin + l16;
#pragma unroll
                for (int mt = 0; mt < 4; mt++)
#pragma unroll
                    for (int r = 0; r < 4; r++) {
                        int t = t0 + mt * 16 + quad * 4 + r;
                        if (t > q) sc[mt][r] = -INFINITY;
                    }
            }

            float rm = -INFINITY;
#pragma unroll
            for (int mt = 0; mt < 4; mt++)
#pragma unroll
                for (int r = 0; r < 4; r++) rm = fmaxf(rm, sc[mt][r]);
            rm = fmaxf(rm, __shfl_xor(rm, 16, 64));
            rm = fmaxf(rm, __shfl_xor(rm, 32, 64));
            float mnew = fmaxf(m_i[g], rm);
            float al = __builtin_amdgcn_exp2f(m_i[g] - mnew);
            m_i[g] = mnew;

            float rs = 0.f;
#pragma unroll
            for (int mt = 0; mt < 4; mt++)
#pragma unroll
                for (int r = 0; r < 4; r++) {
                    float p = __builtin_amdgcn_exp2f(sc[mt][r] - mnew);
                    sc[mt][r] = p;
                    rs += p;
                }
            l_p[g] = l_p[g] * al + rs;           // per-lane partial; combined at end

            // stage P (row q = l16, cols t), XOR-swizzled 16B chunks
            u16* plg = pl + g * 1024;
#pragma unroll
            for (int mt = 0; mt < 4; mt++) {
                uint2 pk;
                pk.x = pack_bf16x2(sc[mt][0], sc[mt][1]);
                pk.y = pack_bf16x2(sc[mt][2], sc[mt][3]);
                int chunk = 2 * mt + (quad >> 1);
                *(uint2*)&plg[l16 * 64 + (chunk ^ (l16 & 7)) * 8 + (quad & 1) * 4] = pk;
            }

            // rescale O^T (cols q = l16 -> alpha is per-lane, no shuffle)
#pragma unroll
            for (int jd = 0; jd < 4; jd++)
#pragma unroll
                for (int r = 0; r < 4; r++) o2[g][jd][r] *= al;

            bf16x8 pb0 = *(const bf16x8*)&plg[l16 * 64 + (quad ^ (l16 & 7)) * 8];
            bf16x8 pb1 = *(const bf16x8*)&plg[l16 * 64 + ((quad + 4) ^ (l16 & 7)) * 8];

            // O^T[d][q] += V^T[d][t] * P[q][t]: A = V-frag, B = P-frag
#pragma unroll
            for (int jd = 0; jd < 4; jd++) {
                o2[g][jd] = __builtin_amdgcn_mfma_f32_16x16x32_bf16(vf[jd][0], pb0, o2[g][jd], 0, 0, 0);
                o2[g][jd] = __builtin_amdgcn_mfma_f32_16x16x32_bf16(vf[jd][1], pb1, o2[g][jd], 0, 0, 0);
            }
        }
    }

    // epilogue: combine l across quads, normalize, transpose via LDS, coalesced store
    int b = bh >> 4, h = bh & (NH - 1);
#pragma unroll
    for (int g = 0; g < 2; g++) {
        float l = l_p[g];
        l += __shfl_xor(l, 16, 64);
        l += __shfl_xor(l, 32, 64);
        float inv = 1.f / l;
        // write O rows: pl2[q=l16][d], d = jd*16 + quad*4 + r  (stride 72 u16)
#pragma unroll
        for (int jd = 0; jd < 4; jd++) {
            uint2 pk;
            pk.x = pack_bf16x2(o2[g][jd][0] * inv, o2[g][jd][1] * inv);
            pk.y = pack_bf16x2(o2[g][jd][2] * inv, o2[g][jd][3] * inv);
            *(uint2*)&pl[l16 * 72 + jd * 16 + quad * 4] = pk;
        }
        int row = lane >> 2, dc = (lane & 3) * 16;
        uint4 d0 = *(const uint4*)&pl[row * 72 + dc];
        uint4 d1 = *(const uint4*)&pl[row * 72 + dc + 8];
        int q = q0w + g * 16 + row;
        size_t addr = (size_t)(b * SEQ + q) * EMB + h * HD + dc;
        *(uint4*)&O[addr] = d0;
        *(uint4*)&O[addr + 8] = d1;
    }
}

extern "C" void kernel_launch(void* const* d_in, const int* in_sizes, int n_in,
                              void* d_out, int out_size, void* d_ws, size_t ws_size,
                              hipStream_t stream) {
    const float* query = (const float*)d_in[0];
    const float* key_  = (const float*)d_in[1];
    const float* value = (const float*)d_in[2];
    const float* Wq = (const float*)d_in[3];
    const float* bq = (const float*)d_in[4];
    const float* Wk = (const float*)d_in[5];
    const float* bk = (const float*)d_in[6];
    const float* Wv = (const float*)d_in[7];
    const float* bv = (const float*)d_in[8];
    const float* Wo = (const float*)d_in[9];
    const float* bo = (const float*)d_in[10];
    float* out = (float*)d_out;

    char* ws = (char*)d_ws;
    const size_t MB = 1u << 20;
    u16* xq  = (u16*)(ws + 0 * MB);
    u16* xk  = (u16*)(ws + 8 * MB);    // reused as Ab (attn out)
    u16* xv  = (u16*)(ws + 16 * MB);
    u16* wqb = (u16*)(ws + 24 * MB);
    u16* wkb = (u16*)(ws + 26 * MB);
    u16* wvb = (u16*)(ws + 28 * MB);
    u16* wob = (u16*)(ws + 30 * MB);
    u16* Qp  = (u16*)(ws + 32 * MB);   // Q with RoPE+scale, [B,H,S,D]
    u16* Kp  = (u16*)(ws + 40 * MB);   // K with RoPE, [B,H,S,D]
    u16* Vt  = (u16*)(ws + 48 * MB);   // V transposed, [B,H,D,S]
    u16* Ab  = xk;

    const int NX = MROWS * EMB;
    const int NW = EMB * EMB;

    k_f2b3<<<dim3(NX / (256 * 8), 1, 3), 256, 0, stream>>>(query, key_, value, xq, xk, xv, NX / 8);
    k_f2b4<<<dim3(NW / (256 * 8), 1, 4), 256, 0, stream>>>(Wq, Wk, Wv, Wo, wqb, wkb, wvb, wob, NW / 8);

    GemmArgs gq = { xq, wqb, bq, Qp, nullptr };
    GemmArgs gk = { xk, wkb, bk, Kp, nullptr };
    GemmArgs gv = { xv, wvb, bv, Vt, nullptr };
    k_gemm_bt<<<dim3(EMB / 128, MROWS / 128, 3), 256, 0, stream>>>(gq, gk, gv, EMB, 0);

    k_attn<<<dim3(16, 32), 256, 0, stream>>>(Qp, Kp, Vt, Ab);

    GemmArgs go = { Ab, wob, bo, nullptr, out };
    k_gemm_bt<<<dim3(EMB / 128, MROWS / 128, 1), 256, 0, stream>>>(go, go, go, EMB, 1);
}